// Round 2
// 689.864 us; speedup vs baseline: 1.0522x; 1.0522x over previous
//
#include <hip/hip_runtime.h>
#include <stdint.h>

#define N_NODES  20000
#define N_EDGES  200000
#define N_SEG    16
#define EXTENT   32
#define N_PATHS  64
#define OP_SIZE  (N_SEG * EXTENT)   // 512
#define MAXK     72   // per-half record capacity: sum of per-pair maxima (<=64) + even-padding (<=8)

// s_waitcnt imm (gfx9): vmcnt[3:0]=b3:0, expcnt=b6:4, lgkmcnt=b11:8, vmcnt[5:4]=b15:14
#define WAIT_VM0  0x0F70   // vmcnt(0), lgkm/exp no-wait
#define WAIT_VM4  0x0F74   // vmcnt(4), lgkm/exp no-wait

// ---------------- CSR build ----------------

__global__ void k_hist(const int* __restrict__ dst, int* __restrict__ offsets) {
    int e = blockIdx.x * blockDim.x + threadIdx.x;
    if (e < N_EDGES) atomicAdd(&offsets[dst[e]], 1);
}

// single block, 1024 threads, LDS-staged exclusive scan (coalesced global I/O)
__global__ __launch_bounds__(1024) void k_scan(int* __restrict__ offsets) {
    __shared__ int buf[N_NODES];     // 80 KB
    __shared__ int wsum[16];
    const int tid = threadIdx.x;
    for (int i = tid; i < N_NODES; i += 1024) buf[i] = offsets[i];
    __syncthreads();
    const int C = (N_NODES + 1023) / 1024;   // 20
    int lo = tid * C;
    int hi = lo + C; if (hi > N_NODES) hi = N_NODES; if (lo > N_NODES) lo = N_NODES;
    int s = 0;
    for (int i = lo; i < hi; ++i) s += buf[i];
    const int lane = tid & 63, w = tid >> 6;
    int v = s;
    for (int d = 1; d < 64; d <<= 1) { int t = __shfl_up(v, d); if (lane >= d) v += t; }
    if (lane == 63) wsum[w] = v;
    __syncthreads();
    int wpre = 0;
    for (int q = 0; q < w; ++q) wpre += wsum[q];
    int acc = wpre + v - s;
    for (int i = lo; i < hi; ++i) { int t = buf[i]; buf[i] = acc; acc += t; }
    __syncthreads();
    for (int i = tid; i < N_NODES; i += 1024) offsets[i] = buf[i];
}

// after scatter, offsets[n] == end(n); start(n) = offsets[n-1], start(0) = 0
__global__ void k_scatter(const int* __restrict__ dst, const int* __restrict__ src,
                          int* __restrict__ offsets, int2* __restrict__ el2) {
    int e = blockIdx.x * blockDim.x + threadIdx.x;
    if (e < N_EDGES) {
        int pos = atomicAdd(&offsets[dst[e]], 1);
        el2[pos] = make_int2(e, src[e]);   // {edge id, src node}
    }
}

// ---------------- path table ----------------
// Segs sorted by count desc, paired adjacently (minimizes sum of max-lengths).
// Slot t: h=0 half computes seg order[2t], h=1 half seg order[2t+1].
// Per-half, fully pre-selected records, packed as int2:
//   .x = (bytesA << 16) | bytesB   where bytesA = i1*EXTENT*4 (x1 operand, buffer-relative)
//                                        bytesB = 2048 + i2*EXTENT*4 (x2 operand)
//   .y = coef bits
// recg[h*MAXK + k].  Per-slot length padded EVEN so k_main can consume records
// in pairs with one ds_read_b128.  Pad records: {2048, 0.0f} (valid addr, zero coef).
__global__ void k_paths(const int* __restrict__ pi, const float* __restrict__ pc,
                        int* __restrict__ ks2g, int2* __restrict__ recg,
                        int* __restrict__ segmap) {
    __shared__ int   s_i1[N_PATHS], s_i2[N_PATHS], s_i3[N_PATHS];
    __shared__ float s_c[N_PATHS];
    __shared__ int2  s_rec[2 * MAXK];
    const int p = threadIdx.x;   // 64 threads
    s_i1[p] = pi[3 * p]; s_i2[p] = pi[3 * p + 1]; s_i3[p] = pi[3 * p + 2];
    s_c[p]  = pc[p];
    for (int q = p; q < 2 * MAXK; q += 64) s_rec[q] = make_int2(2048, 0);  // pad-init all
    __syncthreads();
    if (p == 0) {
        int cnt[N_SEG];
        for (int s = 0; s < N_SEG; ++s) cnt[s] = 0;
        for (int q = 0; q < N_PATHS; ++q) cnt[s_i3[q]]++;
        int order[N_SEG];
        for (int s = 0; s < N_SEG; ++s) order[s] = s;
        for (int a = 1; a < N_SEG; ++a) {           // insertion sort, count desc
            int o = order[a], b = a;
            while (b > 0 && cnt[order[b - 1]] < cnt[o]) { order[b] = order[b - 1]; --b; }
            order[b] = o;
        }
        int ks[9]; ks[0] = 0;
        for (int t = 0; t < 8; ++t) {
            int slo = order[2 * t], shi = order[2 * t + 1];
            segmap[t] = slo; segmap[8 + t] = shi;
            int L = cnt[slo] > cnt[shi] ? cnt[slo] : cnt[shi];
            L += (L & 1);                            // even length per slot
            int wlo = ks[t], whi = ks[t];
            for (int q = 0; q < N_PATHS; ++q) {
                if (s_i3[q] == slo) {
                    s_rec[wlo] = make_int2(((s_i1[q] * EXTENT * 4) << 16) |
                                           (2048 + s_i2[q] * EXTENT * 4),
                                           __float_as_int(s_c[q]));
                    ++wlo;
                }
                if (s_i3[q] == shi) {
                    s_rec[MAXK + whi] = make_int2(((s_i1[q] * EXTENT * 4) << 16) |
                                                  (2048 + s_i2[q] * EXTENT * 4),
                                                  __float_as_int(s_c[q]));
                    ++whi;
                }
            }
            ks[t + 1] = ks[t] + L;
        }
        for (int t = 0; t < 9; ++t) ks2g[t] = ks[t];
    }
    __syncthreads();
    for (int q = p; q < 2 * MAXK; q += 64) recg[q] = s_rec[q];
}

// ---------------- main: 1 wave/node, 1 edge/iter, 2-deep pipelined ----------------

__device__ __forceinline__ void async16(const float* g, float* l) {
    // per-lane 16B global -> wave-uniform LDS base + lane*16
    __builtin_amdgcn_global_load_lds(
        (const __attribute__((address_space(1))) uint32_t*)g,
        (__attribute__((address_space(3))) uint32_t*)l, 16, 0, 0);
}

__device__ __forceinline__ void stage(const float* __restrict__ x_nodes,
                                      const float* __restrict__ x_edges,
                                      int2 m, float* l, int lane) {
    const float* gn = x_nodes + (size_t)m.y * OP_SIZE + lane * 4;
    const float* ge = x_edges + (size_t)m.x * OP_SIZE + lane * 4;
    async16(gn,       l);
    async16(gn + 256, l + 256);
    async16(ge,       l + 512);
    async16(ge + 256, l + 768);
}

__global__ __launch_bounds__(64, 5) void k_main(
    const float* __restrict__ x_nodes, const float* __restrict__ x_edges,
    const int* __restrict__ offsets, const int2* __restrict__ el2,
    const int* __restrict__ ks2g, const int2* __restrict__ recg,
    const int* __restrict__ segmap, float* __restrict__ out)
{
    __shared__ float lds[2 * 1024];   // 2 sets x (x1 row 512 | x2 row 512) = 8 KB
    __shared__ int4  tab[MAXK];       // 1152 B path table, 16B-aligned (ds_read_b128 safe)

    const int lane = threadIdx.x;     // 0..63
    const int xl   = lane & 31;
    const int h    = lane >> 5;       // seg-half
    const int n    = blockIdx.x;

    // stage the table into LDS once per block (int4-wide).
    // Replaces the old per-record global s_load in the inner loop, whose
    // lgkmcnt(0) drain serialized every record against the ds_reads.
    for (int q = lane; q < MAXK; q += 64)          // MAXK int4 == 2*MAXK int2
        tab[q] = ((const int4*)recg)[q];

    int ks2[9];
#pragma unroll
    for (int j = 0; j < 9; ++j) ks2[j] = ks2g[j];
    int myseg[8];
#pragma unroll
    for (int j = 0; j < 8; ++j) myseg[j] = segmap[h * 8 + j];

    const int start = (n == 0) ? 0 : offsets[n - 1];
    const int end   = offsets[n];
    const int deg   = end - start;

    float acc[8];
#pragma unroll
    for (int j = 0; j < 8; ++j) acc[j] = 0.f;

    __syncthreads();   // single wave: drains tab vm-loads + ds_writes before staging

    // h=0 half reads tab[0..35], h=1 half reads tab[36..71] (records pre-selected per half)
    const int4* th = tab + h * (MAXK / 2);

    // prologue: issue edges 0 and 1, prefetch meta for edge 2
    int2 mq = make_int2(0, 0);
    if (deg > 0) stage(x_nodes, x_edges, el2[start],     lds,        lane);
    if (deg > 1) stage(x_nodes, x_edges, el2[start + 1], lds + 1024, lane);
    if (deg > 2) mq = el2[start + 2];

    for (int i = 0; i < deg; ++i) {
        // prefetch meta for edge i+3 (uniform -> scalar load path)
        int2 mf = make_int2(0, 0);
        if (i + 3 < deg) mf = el2[start + i + 3];

        // edge i's 4 staging loads are the oldest outstanding; leave edge i+1's in flight
        if (i + 1 < deg) __builtin_amdgcn_s_waitcnt(WAIT_VM4);
        else             __builtin_amdgcn_s_waitcnt(WAIT_VM0);
        __builtin_amdgcn_sched_barrier(0);

        // buffer-relative byte base for this edge: lane column + buffer toggle
        const char* base = (const char*)lds + ((i & 1) << 12) + (xl << 2);

#pragma unroll
        for (int j = 0; j < 8; ++j) {
            float a = acc[j];
            const int kk1 = ks2[j + 1] >> 1;
            for (int kk = ks2[j] >> 1; kk < kk1; ++kk) {
                int4 q = th[kk];                     // 2 records, one broadcast ds_read_b128
                float p1 = *(const float*)(base + (q.x >> 16));
                float p2 = *(const float*)(base + (q.x & 0xffff));
                a = fmaf(__int_as_float(q.y), p1 * p2, a);
                float p3 = *(const float*)(base + (q.z >> 16));
                float p4 = *(const float*)(base + (q.z & 0xffff));
                a = fmaf(__int_as_float(q.w), p3 * p4, a);
            }
            acc[j] = a;
        }

        // overwrite this set with edge i+2 (ds_reads above already executed;
        // DMA arrival is >> LDS-pipe depth, no hazard)
        if (i + 2 < deg) {
            stage(x_nodes, x_edges, mq, lds + ((i & 1) << 10), lane);
            mq = mf;
        }
    }

    float* row = out + (size_t)n * OP_SIZE;
#pragma unroll
    for (int j = 0; j < 8; ++j)
        row[myseg[j] * EXTENT + xl] = acc[j];
}

// ---------------- launch ----------------

extern "C" void kernel_launch(void* const* d_in, const int* in_sizes, int n_in,
                              void* d_out, int out_size, void* d_ws, size_t ws_size,
                              hipStream_t stream) {
    const float* x_nodes      = (const float*)d_in[0];
    const float* x_edges      = (const float*)d_in[1];
    const float* path_coeffs  = (const float*)d_in[2];
    const int*   src          = (const int*)d_in[3];
    const int*   dst          = (const int*)d_in[4];
    const int*   path_indices = (const int*)d_in[5];
    float* out = (float*)d_out;

    char* ws = (char*)d_ws;
    int*  offsets = (int*)ws;                          ws += N_NODES * sizeof(int);    // 80000
    int2* el2     = (int2*)ws;                         ws += N_EDGES * sizeof(int2);   // 1.6 MB
    int2* recg    = (int2*)ws;                         ws += 2 * MAXK * sizeof(int2);  // 1152
    int*  ks2g    = (int*)ws;                          ws += 16 * sizeof(int);
    int*  segmap  = (int*)ws;

    hipMemsetAsync(offsets, 0, N_NODES * sizeof(int), stream);
    k_hist   <<<(N_EDGES + 255) / 256, 256, 0, stream>>>(dst, offsets);
    k_scan   <<<1, 1024, 0, stream>>>(offsets);
    k_scatter<<<(N_EDGES + 255) / 256, 256, 0, stream>>>(dst, src, offsets, el2);
    k_paths  <<<1, 64, 0, stream>>>(path_indices, path_coeffs, ks2g, recg, segmap);
    k_main   <<<N_NODES, 64, 0, stream>>>(x_nodes, x_edges, offsets, el2,
                                          ks2g, recg, segmap, out);
}